// Round 1
// baseline (737.864 us; speedup 1.0000x reference)
//
#include <hip/hip_runtime.h>
#include <stdint.h>

#define TT   500
#define BB   64
#define IND  256
#define HD   512
#define OD   35
#define ROWS (TT*BB)   // 32000

typedef __attribute__((ext_vector_type(8))) short sh8;   // 8 bf16 (4 VGPRs)
typedef __attribute__((ext_vector_type(4))) float f32x4;

// fp32 scale exactly as numpy computes it: python-double (1.0-0.001)/31 cast to f32 at op time
#define SCALE_F ((float)((1.0 - 0.001) / 31.0))

// ---------------------------------------------------------------- prep weights
// Quantize W -> integer k in [0,31], store as bf16 in [Hp][K] layout.
// Column h==H is all-ones (gives row spike-count n via the same GEMM); h>H is 0.
__global__ __launch_bounds__(256) void k_prep(const float* __restrict__ W1,
                                              const float* __restrict__ W2,
                                              const float* __restrict__ W3,
                                              const float* __restrict__ W4,
                                              uint16_t* __restrict__ wk1,
                                              uint16_t* __restrict__ wk2,
                                              uint16_t* __restrict__ wk3,
                                              uint16_t* __restrict__ wk4) {
  int id = blockIdx.x * 256 + threadIdx.x;
  const float* W; uint16_t* wk; int idx, K, H;
  if (id < 139264)       { idx = id;          W = W1; wk = wk1; K = 256; H = 512; }
  else if (id < 417792)  { idx = id - 139264; W = W2; wk = wk2; K = 512; H = 512; }
  else if (id < 696320)  { idx = id - 417792; W = W3; wk = wk3; K = 512; H = 512; }
  else                   { idx = id - 696320; W = W4; wk = wk4; K = 512; H = 35;  }
  int h = idx / K;           // K is 256 or 512 -> compiler uses shifts per branch? (div ok, once)
  int k = idx - h * K;
  uint16_t bits;
  if (h < H) {
    float w  = W[h * K + k];
    float wc = fminf(1.0f, fmaxf(0.001f, w));
    float v  = (wc - 0.001f) / SCALE_F;     // IEEE div, matches np fp32
    float q  = rintf(v);                    // round-half-even, matches np.round
    bits = (uint16_t)(__float_as_uint(q) >> 16);   // small ints exact in bf16
  } else if (h == H) {
    bits = 0x3F80;  // 1.0 bf16 -> ones column -> n
  } else {
    bits = 0;
  }
  wk[idx] = bits;
}

// ---------------------------------------------------------------- cochlea scan
// One block per batch element; thread i owns chain (b,i). x[b][:] staged in LDS.
// Writes cochlea spikes as bf16 {0,1} in [row=(t*BB+b)][i] layout for GEMM1.
__global__ __launch_bounds__(256) void k_cochlea(const float* __restrict__ x,
                                                 const float* __restrict__ Wch,
                                                 const float* __restrict__ cbetas,
                                                 uint16_t* __restrict__ chs) {
  __shared__ float xs[TT];
  int b = blockIdx.x;
  for (int t = threadIdx.x; t < TT; t += 256) xs[t] = x[b * TT + t];
  __syncthreads();
  int i = threadIdx.x;
  float w    = Wch[i];
  float beta = fminf(1.0f, fmaxf(0.0f, cbetas[i]));
  float mem  = 0.0f;
  for (int t = 0; t < TT; ++t) {
    float cur = __fmul_rn(xs[t], w);                 // outer product element
    int   rs  = (mem > 1.0f);                        // reset from PREVIOUS mem
    float t2  = __fadd_rn(__fmul_rn(beta, mem), cur);
    mem = rs ? __fsub_rn(t2, 1.0f) : t2;
    chs[(size_t)(t * BB + b) * IND + i] = (mem > 1.0f) ? 0x3F80 : 0;
  }
}

// ---------------------------------------------------------------- bf16 MFMA GEMM
// Exact integer GEMM: M[r][h] = sum_i s[r][i] * k[h][i]  (all integers, exact in f32 acc).
// A: [ROWS][K] bf16 spikes; B: [Hp][K] bf16 weights (row h contiguous in k).
// Each wave computes a 32x32 tile (2x2 MFMA 16x16x32 frags). No LDS (v1).
template<int K>
__global__ __launch_bounds__(256) void k_gemm(const uint16_t* __restrict__ A,
                                              const uint16_t* __restrict__ B,
                                              uint16_t* __restrict__ M,
                                              int Hp, int colpairs) {
  int wid  = (blockIdx.x * 256 + threadIdx.x) >> 6;
  int lane = threadIdx.x & 63;
  int rp = wid / colpairs;
  int cp = wid - rp * colpairs;
  int r0 = rp * 32, c0 = cp * 32;
  int lr = lane & 15;
  int lk = (lane >> 4) * 8;      // A[m=lane&15][k=(lane>>4)*8+j] (verified layout)
  const uint16_t* a0p = A + (size_t)(r0 + lr) * K + lk;
  const uint16_t* a1p = A + (size_t)(r0 + 16 + lr) * K + lk;
  const uint16_t* b0p = B + (size_t)(c0 + lr) * K + lk;
  const uint16_t* b1p = B + (size_t)(c0 + 16 + lr) * K + lk;
  f32x4 acc00 = {0,0,0,0}, acc01 = {0,0,0,0}, acc10 = {0,0,0,0}, acc11 = {0,0,0,0};
#pragma unroll 4
  for (int k = 0; k < K / 32; ++k) {
    sh8 a0 = *(const sh8*)(a0p + k * 32);
    sh8 a1 = *(const sh8*)(a1p + k * 32);
    sh8 b0 = *(const sh8*)(b0p + k * 32);
    sh8 b1 = *(const sh8*)(b1p + k * 32);
    acc00 = __builtin_amdgcn_mfma_f32_16x16x32_bf16(a0, b0, acc00, 0, 0, 0);
    acc01 = __builtin_amdgcn_mfma_f32_16x16x32_bf16(a0, b1, acc01, 0, 0, 0);
    acc10 = __builtin_amdgcn_mfma_f32_16x16x32_bf16(a1, b0, acc10, 0, 0, 0);
    acc11 = __builtin_amdgcn_mfma_f32_16x16x32_bf16(a1, b1, acc11, 0, 0, 0);
  }
  // C/D layout (verified): col = lane&15, row = (lane>>4)*4 + reg
  int oc = lane & 15;
#pragma unroll
  for (int i = 0; i < 4; ++i) {
    int orow = (lane >> 4) * 4 + i;
    M[(size_t)(r0 + orow) * Hp + c0 + oc]           = (uint16_t)acc00[i];
    M[(size_t)(r0 + orow) * Hp + c0 + 16 + oc]      = (uint16_t)acc01[i];
    M[(size_t)(r0 + 16 + orow) * Hp + c0 + oc]      = (uint16_t)acc10[i];
    M[(size_t)(r0 + 16 + orow) * Hp + c0 + 16 + oc] = (uint16_t)acc11[i];
  }
}

// ---------------------------------------------------------------- LIF scan
// Thread owns chain (b,h); reconstructs cur = m*scale + n*wmin (double, then f32),
// runs the LIF recurrence with np-exact op-by-op fp32 rounding.
template<int H, int Hp, bool WS, bool WM, int UNR>
__global__ __launch_bounds__(256) void k_scan(const uint16_t* __restrict__ M,
                                              const float* __restrict__ pbeta,
                                              float* __restrict__ spk_out,
                                              uint16_t* __restrict__ s_out,
                                              float* __restrict__ mem_out) {
  int tid = blockIdx.x * 256 + threadIdx.x;
  if (tid >= BB * H) return;
  int b = tid / H;
  int h = tid - b * H;
  float beta = fminf(1.0f, fmaxf(0.0f, *pbeta));
  const double DSCALE = (double)SCALE_F;
  const double DWMIN  = (double)0.001f;
  float mem = 0.0f;
  for (int t0 = 0; t0 < TT; t0 += UNR) {
    uint16_t mv[UNR], nv[UNR];
#pragma unroll
    for (int j = 0; j < UNR; ++j) {
      size_t row = (size_t)(t0 + j) * BB + b;
      mv[j] = M[row * Hp + h];
      nv[j] = M[row * Hp + H];    // ones-column = spike count n
    }
#pragma unroll
    for (int j = 0; j < UNR; ++j) {
      int t = t0 + j;
      float cur = (float)((double)mv[j] * DSCALE + (double)nv[j] * DWMIN);
      int   rs  = (mem > 1.0f);
      float t2  = __fadd_rn(__fmul_rn(beta, mem), cur);
      mem = rs ? __fsub_rn(t2, 1.0f) : t2;
      int spk = (mem > 1.0f);
      spk_out[(size_t)t * (BB * H) + tid] = spk ? 1.0f : 0.0f;
      if (WS) s_out[((size_t)(t * BB + b)) * H + h] = spk ? 0x3F80 : 0;
      if (WM) mem_out[(size_t)t * (BB * H) + tid] = mem;
    }
  }
}

// ---------------------------------------------------------------- launch
extern "C" void kernel_launch(void* const* d_in, const int* in_sizes, int n_in,
                              void* d_out, int out_size, void* d_ws, size_t ws_size,
                              hipStream_t stream) {
  const float* x      = (const float*)d_in[0];
  const float* Wch    = (const float*)d_in[1];
  const float* W1     = (const float*)d_in[2];
  const float* W2     = (const float*)d_in[3];
  const float* W3     = (const float*)d_in[4];
  const float* W4     = (const float*)d_in[5];
  const float* cbetas = (const float*)d_in[6];
  const float* b1     = (const float*)d_in[7];
  const float* b2     = (const float*)d_in[8];
  const float* b3     = (const float*)d_in[9];
  const float* b4     = (const float*)d_in[10];

  uint8_t* ws = (uint8_t*)d_ws;
  // weights bf16: [Hp][K]; Hp = 544 (512 + ones col + pad) or 64 for layer 4
  uint16_t* wk1 = (uint16_t*)(ws + 0);          // 544*256*2 = 278528
  uint16_t* wk2 = (uint16_t*)(ws + 278528);     // 544*512*2 = 557056
  uint16_t* wk3 = (uint16_t*)(ws + 835584);     // 557056
  uint16_t* wk4 = (uint16_t*)(ws + 1392640);    // 64*512*2 = 65536
  uint16_t* chs  = (uint16_t*)(ws + 1458176);   // 32000*256*2 = 16384000
  uint16_t* sbuf = (uint16_t*)(ws + 17842176);  // 32000*512*2 = 32768000 (reused s1/s2/s3)
  uint16_t* mbuf = (uint16_t*)(ws + 50610176);  // 32000*544*2 = 34816000 (reused cur1..4)

  float* out  = (float*)d_out;
  float* spk1 = out;                // 500*64*512
  float* spk2 = out + 16384000;
  float* spk3 = out + 32768000;
  float* spk4 = out + 49152000;     // 500*64*35
  float* mem4 = out + 50272000;

  k_prep<<<2848, 256, 0, stream>>>(W1, W2, W3, W4, wk1, wk2, wk3, wk4);
  k_cochlea<<<BB, 256, 0, stream>>>(x, Wch, cbetas, chs);

  // layer 1: K=256, Hp=544, colpairs=17 -> waves = 1000*17, blocks = 17000/4
  k_gemm<256><<<4250, 256, 0, stream>>>(chs, wk1, mbuf, 544, 17);
  k_scan<512, 544, true, false, 10><<<128, 256, 0, stream>>>(mbuf, b1, spk1, sbuf, nullptr);

  k_gemm<512><<<4250, 256, 0, stream>>>(sbuf, wk2, mbuf, 544, 17);
  k_scan<512, 544, true, false, 10><<<128, 256, 0, stream>>>(mbuf, b2, spk2, sbuf, nullptr);

  k_gemm<512><<<4250, 256, 0, stream>>>(sbuf, wk3, mbuf, 544, 17);
  k_scan<512, 544, true, false, 10><<<128, 256, 0, stream>>>(mbuf, b3, spk3, sbuf, nullptr);

  // layer 4: Hp=64, colpairs=2 -> waves = 1000*2, blocks = 500
  k_gemm<512><<<500, 256, 0, stream>>>(sbuf, wk4, mbuf, 64, 2);
  k_scan<35, 64, false, true, 10><<<9, 256, 0, stream>>>(mbuf, b4, spk4, nullptr, mem4);
}

// Round 2
// 673.469 us; speedup vs baseline: 1.0956x; 1.0956x over previous
//
#include <hip/hip_runtime.h>
#include <stdint.h>

#define TT   500
#define BB   64
#define IND  256
#define HD   512
#define OD   35
#define ROWS (TT*BB)   // 32000

typedef __attribute__((ext_vector_type(8))) short sh8;   // 8 bf16 (4 VGPRs)
typedef __attribute__((ext_vector_type(4))) float f32x4;

// fp32 scale exactly as numpy computes it
#define SCALE_F ((float)((1.0 - 0.001) / 31.0))

// ---------------------------------------------------------------- prep weights
// Quantize W -> integer k in [0,31], store as bf16 in [H][K] layout (no ones col).
// wk4 padded to 64 rows (h>=35 zero).
__global__ __launch_bounds__(256) void k_prep(const float* __restrict__ W1,
                                              const float* __restrict__ W2,
                                              const float* __restrict__ W3,
                                              const float* __restrict__ W4,
                                              uint16_t* __restrict__ wk1,
                                              uint16_t* __restrict__ wk2,
                                              uint16_t* __restrict__ wk3,
                                              uint16_t* __restrict__ wk4) {
  int id = blockIdx.x * 256 + threadIdx.x;
  const float* W; uint16_t* wk; int idx, K, H;
  if (id < 131072)       { idx = id;          W = W1; wk = wk1; K = 256; H = 512; }
  else if (id < 393216)  { idx = id - 131072; W = W2; wk = wk2; K = 512; H = 512; }
  else if (id < 655360)  { idx = id - 393216; W = W3; wk = wk3; K = 512; H = 512; }
  else                   { idx = id - 655360; W = W4; wk = wk4; K = 512; H = 35;  }
  int h = idx / K;
  int k = idx - h * K;
  uint16_t bits = 0;
  if (h < H) {
    float w  = W[h * K + k];
    float wc = fminf(1.0f, fmaxf(0.001f, w));
    float v  = (wc - 0.001f) / SCALE_F;
    float q  = rintf(v);                            // round-half-even, matches np.round
    bits = (uint16_t)(__float_as_uint(q) >> 16);    // small ints exact in bf16
  }
  wk[idx] = bits;
}

// ---------------------------------------------------------------- cochlea scan
// One block per batch element; thread i owns chain (b,i). Also emits per-row
// spike count n_ch[row] via ballot+popcount (1 atomic per wave per t).
__global__ __launch_bounds__(256) void k_cochlea(const float* __restrict__ x,
                                                 const float* __restrict__ Wch,
                                                 const float* __restrict__ cbetas,
                                                 uint16_t* __restrict__ chs,
                                                 int* __restrict__ n_ch) {
  __shared__ float xs[TT];
  int b = blockIdx.x;
  for (int t = threadIdx.x; t < TT; t += 256) xs[t] = x[b * TT + t];
  __syncthreads();
  int i = threadIdx.x;
  float w    = Wch[i];
  float beta = fminf(1.0f, fmaxf(0.0f, cbetas[i]));
  float mem  = 0.0f;
  for (int t = 0; t < TT; ++t) {
    float cur = __fmul_rn(xs[t], w);
    int   rs  = (mem > 1.0f);
    float t2  = __fadd_rn(__fmul_rn(beta, mem), cur);
    mem = rs ? __fsub_rn(t2, 1.0f) : t2;
    int spk = (mem > 1.0f);
    int row = t * BB + b;
    chs[(size_t)row * IND + i] = spk ? 0x3F80 : 0;
    unsigned long long bal = __ballot(spk);
    if ((threadIdx.x & 63) == 0) atomicAdd(n_ch + row, (int)__popcll(bal));
  }
}

// ---------------------------------------------------------------- bf16 MFMA GEMM
// Exact integer GEMM. Each wave computes a 64x64 tile as 4x4 MFMA 16x16x32 frags:
// per k-step 8 loads -> 16 MFMAs (2:1). A:[ROWS][K], B:[Hp][K] row-major bf16.
template<int K>
__global__ __launch_bounds__(256) void k_gemm(const uint16_t* __restrict__ A,
                                              const uint16_t* __restrict__ B,
                                              uint16_t* __restrict__ M,
                                              int Hp, int coltiles) {
  int wid  = (blockIdx.x * 256 + threadIdx.x) >> 6;
  int lane = threadIdx.x & 63;
  int rt = wid / coltiles;
  int ct = wid - rt * coltiles;
  int r0 = rt * 64, c0 = ct * 64;
  int lr = lane & 15;
  int lk = (lane >> 4) * 8;      // A[m=lane&15][k=(lane>>4)*8+j]
  const uint16_t* ap = A + (size_t)(r0 + lr) * K + lk;
  const uint16_t* bp = B + (size_t)(c0 + lr) * K + lk;
  f32x4 acc[4][4];
#pragma unroll
  for (int i = 0; i < 4; ++i)
#pragma unroll
    for (int j = 0; j < 4; ++j) acc[i][j] = (f32x4){0, 0, 0, 0};

#pragma unroll 2
  for (int k = 0; k < K / 32; ++k) {
    sh8 a[4], b[4];
#pragma unroll
    for (int s = 0; s < 4; ++s) {
      a[s] = *(const sh8*)(ap + (size_t)s * 16 * K + k * 32);
      b[s] = *(const sh8*)(bp + (size_t)s * 16 * K + k * 32);
    }
#pragma unroll
    for (int ar = 0; ar < 4; ++ar)
#pragma unroll
      for (int cs = 0; cs < 4; ++cs)
        acc[ar][cs] = __builtin_amdgcn_mfma_f32_16x16x32_bf16(a[ar], b[cs], acc[ar][cs], 0, 0, 0);
  }
  // C/D layout: col = lane&15, row = (lane>>4)*4 + reg
  int oc = lane & 15;
  int rb = (lane >> 4) * 4;
#pragma unroll
  for (int ar = 0; ar < 4; ++ar)
#pragma unroll
    for (int i = 0; i < 4; ++i) {
      size_t rowoff = (size_t)(r0 + ar * 16 + rb + i) * Hp;
#pragma unroll
      for (int cs = 0; cs < 4; ++cs)
        M[rowoff + c0 + cs * 16 + oc] = (uint16_t)acc[ar][cs][i];
    }
}

// ---------------------------------------------------------------- LIF scan
// Thread owns chain (b,h); cur = m*scale + n*wmin (double, then f32), np-exact
// fp32 recurrence. Optionally emits bf16 spikes + per-row spike counts for the
// next layer (ballot+popcount, valid because b is wave-uniform when H=512).
template<int H, int Hp, bool WS, bool WM, bool WN, int UNR>
__global__ __launch_bounds__(256) void k_scan(const uint16_t* __restrict__ M,
                                              const int* __restrict__ nrow,
                                              const float* __restrict__ pbeta,
                                              float* __restrict__ spk_out,
                                              uint16_t* __restrict__ s_out,
                                              int* __restrict__ n_out,
                                              float* __restrict__ mem_out) {
  int tid = blockIdx.x * 256 + threadIdx.x;
  if (tid >= BB * H) return;
  int b = tid / H;
  int h = tid - b * H;
  float beta = fminf(1.0f, fmaxf(0.0f, *pbeta));
  const double DSCALE = (double)SCALE_F;
  const double DWMIN  = (double)0.001f;
  float mem = 0.0f;
  for (int t0 = 0; t0 < TT; t0 += UNR) {
    uint16_t mv[UNR]; int nv[UNR];
#pragma unroll
    for (int j = 0; j < UNR; ++j) {
      int row = (t0 + j) * BB + b;
      mv[j] = M[(size_t)row * Hp + h];
      nv[j] = nrow[row];
    }
#pragma unroll
    for (int j = 0; j < UNR; ++j) {
      int t = t0 + j;
      int row = t * BB + b;
      float cur = (float)((double)mv[j] * DSCALE + (double)nv[j] * DWMIN);
      int   rs  = (mem > 1.0f);
      float t2  = __fadd_rn(__fmul_rn(beta, mem), cur);
      mem = rs ? __fsub_rn(t2, 1.0f) : t2;
      int spk = (mem > 1.0f);
      spk_out[(size_t)t * (BB * H) + tid] = spk ? 1.0f : 0.0f;
      if (WS) s_out[(size_t)row * H + h] = spk ? 0x3F80 : 0;
      if (WN) {
        unsigned long long bal = __ballot(spk);
        if ((threadIdx.x & 63) == 0) atomicAdd(n_out + row, (int)__popcll(bal));
      }
      if (WM) mem_out[(size_t)t * (BB * H) + tid] = mem;
    }
  }
}

// ---------------------------------------------------------------- launch
extern "C" void kernel_launch(void* const* d_in, const int* in_sizes, int n_in,
                              void* d_out, int out_size, void* d_ws, size_t ws_size,
                              hipStream_t stream) {
  const float* x      = (const float*)d_in[0];
  const float* Wch    = (const float*)d_in[1];
  const float* W1     = (const float*)d_in[2];
  const float* W2     = (const float*)d_in[3];
  const float* W3     = (const float*)d_in[4];
  const float* W4     = (const float*)d_in[5];
  const float* cbetas = (const float*)d_in[6];
  const float* b1     = (const float*)d_in[7];
  const float* b2     = (const float*)d_in[8];
  const float* b3     = (const float*)d_in[9];
  const float* b4     = (const float*)d_in[10];

  uint8_t* ws = (uint8_t*)d_ws;
  uint16_t* wk1  = (uint16_t*)(ws + 0);         // 512*256*2 = 262144
  uint16_t* wk2  = (uint16_t*)(ws + 262144);    // 512*512*2 = 524288
  uint16_t* wk3  = (uint16_t*)(ws + 786432);    // 524288
  uint16_t* wk4  = (uint16_t*)(ws + 1310720);   // 64*512*2 = 65536
  int*      n_ch = (int*)(ws + 1376256);        // 32000*4 = 128000
  int*      n1   = (int*)(ws + 1504256);
  int*      n2   = (int*)(ws + 1632256);
  int*      n3   = (int*)(ws + 1760256);        // ends 1888256
  uint16_t* chs  = (uint16_t*)(ws + 1888256);   // 32000*256*2 = 16384000
  uint16_t* sbuf = (uint16_t*)(ws + 18272256);  // 32000*512*2 = 32768000
  uint16_t* mbuf = (uint16_t*)(ws + 51040256);  // 32768000

  float* out  = (float*)d_out;
  float* spk1 = out;                // 500*64*512
  float* spk2 = out + 16384000;
  float* spk3 = out + 32768000;
  float* spk4 = out + 49152000;     // 500*64*35
  float* mem4 = out + 50272000;

  // zero the 4 contiguous spike-count buffers (atomic accumulators)
  hipMemsetAsync(ws + 1376256, 0, 512000, stream);

  k_prep<<<2688, 256, 0, stream>>>(W1, W2, W3, W4, wk1, wk2, wk3, wk4);
  k_cochlea<<<BB, 256, 0, stream>>>(x, Wch, cbetas, chs, n_ch);

  // layers: GEMM 64x64/wave; L1-3: 500 rowtiles x 8 coltiles = 4000 waves
  k_gemm<256><<<1000, 256, 0, stream>>>(chs, wk1, mbuf, 512, 8);
  k_scan<512, 512, true, false, true, 10><<<128, 256, 0, stream>>>(mbuf, n_ch, b1, spk1, sbuf, n1, nullptr);

  k_gemm<512><<<1000, 256, 0, stream>>>(sbuf, wk2, mbuf, 512, 8);
  k_scan<512, 512, true, false, true, 10><<<128, 256, 0, stream>>>(mbuf, n1, b2, spk2, sbuf, n2, nullptr);

  k_gemm<512><<<1000, 256, 0, stream>>>(sbuf, wk3, mbuf, 512, 8);
  k_scan<512, 512, true, false, true, 10><<<128, 256, 0, stream>>>(mbuf, n2, b3, spk3, sbuf, n3, nullptr);

  // layer 4: Hp=64, 1 coltile -> 500 waves
  k_gemm<512><<<125, 256, 0, stream>>>(sbuf, wk4, mbuf, 64, 1);
  k_scan<35, 64, false, true, false, 10><<<9, 256, 0, stream>>>(mbuf, n3, b4, spk4, nullptr, nullptr, mem4);
}

// Round 3
// 573.037 us; speedup vs baseline: 1.2876x; 1.1753x over previous
//
#include <hip/hip_runtime.h>
#include <stdint.h>

#define TT   500
#define BB   64
#define IND  256
#define HD   512
#define OD   35
#define ROWS (TT*BB)   // 32000

typedef __attribute__((ext_vector_type(8))) short sh8;   // 8 bf16 (4 VGPRs)
typedef __attribute__((ext_vector_type(4))) float f32x4;

// fp32 scale exactly as numpy computes it
#define SCALE_F ((float)((1.0 - 0.001) / 31.0))

__device__ __forceinline__ void load16_lds(const uint16_t* g, uint16_t* l) {
  __builtin_amdgcn_global_load_lds((const __attribute__((address_space(1))) void*)g,
                                   (__attribute__((address_space(3))) void*)l, 16, 0, 0);
}

// ---------------------------------------------------------------- prep weights
__global__ __launch_bounds__(256) void k_prep(const float* __restrict__ W1,
                                              const float* __restrict__ W2,
                                              const float* __restrict__ W3,
                                              const float* __restrict__ W4,
                                              uint16_t* __restrict__ wk1,
                                              uint16_t* __restrict__ wk2,
                                              uint16_t* __restrict__ wk3,
                                              uint16_t* __restrict__ wk4) {
  int id = blockIdx.x * 256 + threadIdx.x;
  const float* W; uint16_t* wk; int idx, K, H;
  if (id < 131072)       { idx = id;          W = W1; wk = wk1; K = 256; H = 512; }
  else if (id < 393216)  { idx = id - 131072; W = W2; wk = wk2; K = 512; H = 512; }
  else if (id < 655360)  { idx = id - 393216; W = W3; wk = wk3; K = 512; H = 512; }
  else                   { idx = id - 655360; W = W4; wk = wk4; K = 512; H = 35;  }
  int h = idx / K;
  int k = idx - h * K;
  uint16_t bits = 0;
  if (h < H) {
    float w  = W[h * K + k];
    float wc = fminf(1.0f, fmaxf(0.001f, w));
    float v  = (wc - 0.001f) / SCALE_F;
    float q  = rintf(v);                            // round-half-even, matches np.round
    bits = (uint16_t)(__float_as_uint(q) >> 16);    // small ints exact in bf16
  }
  wk[idx] = bits;
}

// ---------------------------------------------------------------- cochlea scan
// 64-thread blocks, 4 blocks per batch element -> spreads over all 256 CUs.
__global__ __launch_bounds__(64) void k_cochlea(const float* __restrict__ x,
                                                const float* __restrict__ Wch,
                                                const float* __restrict__ cbetas,
                                                uint16_t* __restrict__ chs,
                                                int* __restrict__ n_ch) {
  __shared__ float xs[TT];
  int b = blockIdx.x >> 2;
  int i = (blockIdx.x & 3) * 64 + threadIdx.x;
  for (int t = threadIdx.x; t < TT; t += 64) xs[t] = x[b * TT + t];
  __syncthreads();
  float w    = Wch[i];
  float beta = fminf(1.0f, fmaxf(0.0f, cbetas[i]));
  float mem  = 0.0f;
  for (int t = 0; t < TT; ++t) {
    float cur = __fmul_rn(xs[t], w);
    int   rs  = (mem > 1.0f);
    float t2  = __fadd_rn(__fmul_rn(beta, mem), cur);
    mem = rs ? __fsub_rn(t2, 1.0f) : t2;
    int spk = (mem > 1.0f);
    int row = t * BB + b;
    chs[(size_t)row * IND + i] = spk ? 0x3F80 : 0;
    unsigned long long bal = __ballot(spk);
    if (threadIdx.x == 0) atomicAdd(n_ch + row, (int)__popcll(bal));
  }
}

// ---------------------------------------------------------------- LDS MFMA GEMM
// m97-style: 128x128 block tile (4 waves, 64x64 each), BK=64, global_load_lds
// width-16 staging with XOR bank swizzle (slot = chunk ^ (row&7)); exact
// integer bf16 GEMM, f32 accum. A:[ROWS][K], B:[128*coltiles][K] row-major.
template<int K>
__global__ __launch_bounds__(256) void k_gemm_lds(const uint16_t* __restrict__ A,
                                                  const uint16_t* __restrict__ B,
                                                  uint16_t* __restrict__ M,
                                                  int Hp, int coltiles) {
  __shared__ uint16_t As[128 * 64];   // [row][slot*8..], row stride 128 B
  __shared__ uint16_t Bs[128 * 64];
  int tid  = threadIdx.x;
  int lane = tid & 63, w = tid >> 6;
  int rt = blockIdx.x / coltiles, ct = blockIdx.x - rt * coltiles;
  int r0 = rt * 128, c0 = ct * 128;
  int wr = (w >> 1) * 64, wc = (w & 1) * 64;   // wave's 64x64 subtile
  int lr = lane & 15, kgf = lane >> 4;
  f32x4 acc[4][4];
#pragma unroll
  for (int i = 0; i < 4; ++i)
#pragma unroll
    for (int j = 0; j < 4; ++j) acc[i][j] = (f32x4){0, 0, 0, 0};

  for (int k0 = 0; k0 < K; k0 += 64) {
    __syncthreads();   // previous iter's ds_reads complete before overwrite
#pragma unroll
    for (int i = 0; i < 4; ++i) {
      int L = i * 256 + tid;          // chunk index; wave covers 64 consecutive
      int row = L >> 3, c = L & 7;
      int kg = c ^ (row & 7);         // slot c stores global chunk kg
      load16_lds(A + (size_t)(r0 + row) * K + k0 + kg * 8,
                 &As[(i * 256 + w * 64) * 8]);
    }
#pragma unroll
    for (int i = 0; i < 4; ++i) {
      int L = i * 256 + tid;
      int row = L >> 3, c = L & 7;
      int kg = c ^ (row & 7);
      load16_lds(B + (size_t)(c0 + row) * K + k0 + kg * 8,
                 &Bs[(i * 256 + w * 64) * 8]);
    }
    __syncthreads();   // staged data visible (drains vmcnt)
#pragma unroll
    for (int kk = 0; kk < 2; ++kk) {
      sh8 a[4], b[4];
#pragma unroll
      for (int s = 0; s < 4; ++s) {
        int arow = wr + s * 16 + lr;
        int sa   = (kk * 4 + kgf) ^ (arow & 7);
        a[s] = *(const sh8*)&As[arow * 64 + sa * 8];
        int brow = wc + s * 16 + lr;
        int sb   = (kk * 4 + kgf) ^ (brow & 7);
        b[s] = *(const sh8*)&Bs[brow * 64 + sb * 8];
      }
#pragma unroll
      for (int ar = 0; ar < 4; ++ar)
#pragma unroll
        for (int cs = 0; cs < 4; ++cs)
          acc[ar][cs] = __builtin_amdgcn_mfma_f32_16x16x32_bf16(a[ar], b[cs], acc[ar][cs], 0, 0, 0);
    }
  }
  // C/D layout: col = lane&15, row = (lane>>4)*4 + reg
  int oc = lane & 15;
  int rb = (lane >> 4) * 4;
#pragma unroll
  for (int ar = 0; ar < 4; ++ar)
#pragma unroll
    for (int i = 0; i < 4; ++i) {
      size_t rowoff = (size_t)(r0 + wr + ar * 16 + rb + i) * Hp;
#pragma unroll
      for (int cs = 0; cs < 4; ++cs)
        M[rowoff + c0 + wc + cs * 16 + oc] = (uint16_t)acc[ar][cs][i];
    }
}

// ---------------------------------------------------------------- naive GEMM (layer 4, tiny)
template<int K>
__global__ __launch_bounds__(256) void k_gemm_naive(const uint16_t* __restrict__ A,
                                                    const uint16_t* __restrict__ B,
                                                    uint16_t* __restrict__ M,
                                                    int Hp, int coltiles) {
  int wid  = (blockIdx.x * 256 + threadIdx.x) >> 6;
  int lane = threadIdx.x & 63;
  int rt = wid / coltiles;
  int ct = wid - rt * coltiles;
  int r0 = rt * 64, c0 = ct * 64;
  int lr = lane & 15;
  int lk = (lane >> 4) * 8;
  const uint16_t* ap = A + (size_t)(r0 + lr) * K + lk;
  const uint16_t* bp = B + (size_t)(c0 + lr) * K + lk;
  f32x4 acc[4][4];
#pragma unroll
  for (int i = 0; i < 4; ++i)
#pragma unroll
    for (int j = 0; j < 4; ++j) acc[i][j] = (f32x4){0, 0, 0, 0};
#pragma unroll 2
  for (int k = 0; k < K / 32; ++k) {
    sh8 a[4], b[4];
#pragma unroll
    for (int s = 0; s < 4; ++s) {
      a[s] = *(const sh8*)(ap + (size_t)s * 16 * K + k * 32);
      b[s] = *(const sh8*)(bp + (size_t)s * 16 * K + k * 32);
    }
#pragma unroll
    for (int ar = 0; ar < 4; ++ar)
#pragma unroll
      for (int cs = 0; cs < 4; ++cs)
        acc[ar][cs] = __builtin_amdgcn_mfma_f32_16x16x32_bf16(a[ar], b[cs], acc[ar][cs], 0, 0, 0);
  }
  int oc = lane & 15;
  int rb = (lane >> 4) * 4;
#pragma unroll
  for (int ar = 0; ar < 4; ++ar)
#pragma unroll
    for (int i = 0; i < 4; ++i) {
      size_t rowoff = (size_t)(r0 + ar * 16 + rb + i) * Hp;
#pragma unroll
      for (int cs = 0; cs < 4; ++cs)
        M[rowoff + c0 + cs * 16 + oc] = (uint16_t)acc[ar][cs][i];
    }
}

// ---------------------------------------------------------------- LIF scan
// 64-thread blocks -> spreads over all CUs. np-exact fp32 recurrence.
template<int H, int Hp, bool WS, bool WM, bool WN, int UNR>
__global__ __launch_bounds__(64) void k_scan(const uint16_t* __restrict__ M,
                                             const int* __restrict__ nrow,
                                             const float* __restrict__ pbeta,
                                             float* __restrict__ spk_out,
                                             uint16_t* __restrict__ s_out,
                                             int* __restrict__ n_out,
                                             float* __restrict__ mem_out) {
  int tid = blockIdx.x * 64 + threadIdx.x;
  if (tid >= BB * H) return;
  int b = tid / H;
  int h = tid - b * H;
  float beta = fminf(1.0f, fmaxf(0.0f, *pbeta));
  const double DSCALE = (double)SCALE_F;
  const double DWMIN  = (double)0.001f;
  float mem = 0.0f;
  for (int t0 = 0; t0 < TT; t0 += UNR) {
    uint16_t mv[UNR]; int nv[UNR];
#pragma unroll
    for (int j = 0; j < UNR; ++j) {
      int row = (t0 + j) * BB + b;
      mv[j] = M[(size_t)row * Hp + h];
      nv[j] = nrow[row];
    }
#pragma unroll
    for (int j = 0; j < UNR; ++j) {
      int t = t0 + j;
      int row = t * BB + b;
      float cur = (float)((double)mv[j] * DSCALE + (double)nv[j] * DWMIN);
      int   rs  = (mem > 1.0f);
      float t2  = __fadd_rn(__fmul_rn(beta, mem), cur);
      mem = rs ? __fsub_rn(t2, 1.0f) : t2;
      int spk = (mem > 1.0f);
      spk_out[(size_t)t * (BB * H) + tid] = spk ? 1.0f : 0.0f;
      if (WS) s_out[(size_t)row * H + h] = spk ? 0x3F80 : 0;
      if (WN) {
        unsigned long long bal = __ballot(spk);
        if (threadIdx.x == 0) atomicAdd(n_out + row, (int)__popcll(bal));
      }
      if (WM) mem_out[(size_t)t * (BB * H) + tid] = mem;
    }
  }
}

// ---------------------------------------------------------------- launch
extern "C" void kernel_launch(void* const* d_in, const int* in_sizes, int n_in,
                              void* d_out, int out_size, void* d_ws, size_t ws_size,
                              hipStream_t stream) {
  const float* x      = (const float*)d_in[0];
  const float* Wch    = (const float*)d_in[1];
  const float* W1     = (const float*)d_in[2];
  const float* W2     = (const float*)d_in[3];
  const float* W3     = (const float*)d_in[4];
  const float* W4     = (const float*)d_in[5];
  const float* cbetas = (const float*)d_in[6];
  const float* b1     = (const float*)d_in[7];
  const float* b2     = (const float*)d_in[8];
  const float* b3     = (const float*)d_in[9];
  const float* b4     = (const float*)d_in[10];

  uint8_t* ws = (uint8_t*)d_ws;
  uint16_t* wk1  = (uint16_t*)(ws + 0);         // 512*256*2 = 262144
  uint16_t* wk2  = (uint16_t*)(ws + 262144);    // 512*512*2 = 524288
  uint16_t* wk3  = (uint16_t*)(ws + 786432);    // 524288
  uint16_t* wk4  = (uint16_t*)(ws + 1310720);   // 64*512*2 = 65536
  int*      n_ch = (int*)(ws + 1376256);        // 32000*4 each
  int*      n1   = (int*)(ws + 1504256);
  int*      n2   = (int*)(ws + 1632256);
  int*      n3   = (int*)(ws + 1760256);        // ends 1888256
  uint16_t* chs  = (uint16_t*)(ws + 1888256);   // 32000*256*2 = 16384000
  uint16_t* sbuf = (uint16_t*)(ws + 18272256);  // 32000*512*2 = 32768000
  uint16_t* mbuf = (uint16_t*)(ws + 51040256);  // 32768000

  float* out  = (float*)d_out;
  float* spk1 = out;                // 500*64*512
  float* spk2 = out + 16384000;
  float* spk3 = out + 32768000;
  float* spk4 = out + 49152000;     // 500*64*35
  float* mem4 = out + 50272000;

  hipMemsetAsync(ws + 1376256, 0, 512000, stream);

  k_prep<<<2688, 256, 0, stream>>>(W1, W2, W3, W4, wk1, wk2, wk3, wk4);
  k_cochlea<<<256, 64, 0, stream>>>(x, Wch, cbetas, chs, n_ch);

  // L1-3: 250 rowtiles x 4 coltiles = 1000 blocks of 128x128
  k_gemm_lds<256><<<1000, 256, 0, stream>>>(chs, wk1, mbuf, 512, 4);
  k_scan<512, 512, true, false, true, 10><<<512, 64, 0, stream>>>(mbuf, n_ch, b1, spk1, sbuf, n1, nullptr);

  k_gemm_lds<512><<<1000, 256, 0, stream>>>(sbuf, wk2, mbuf, 512, 4);
  k_scan<512, 512, true, false, true, 10><<<512, 64, 0, stream>>>(mbuf, n1, b2, spk2, sbuf, n2, nullptr);

  k_gemm_lds<512><<<1000, 256, 0, stream>>>(sbuf, wk3, mbuf, 512, 4);
  k_scan<512, 512, true, false, true, 10><<<512, 64, 0, stream>>>(mbuf, n2, b3, spk3, sbuf, n3, nullptr);

  // layer 4: tiny (N=35 -> Hp=64), naive path: 500 waves = 125 blocks
  k_gemm_naive<512><<<125, 256, 0, stream>>>(sbuf, wk4, mbuf, 64, 1);
  k_scan<35, 64, false, true, false, 10><<<35, 64, 0, stream>>>(mbuf, n3, b4, spk4, nullptr, nullptr, mem4);
}